// Round 4
// baseline (1773.353 us; speedup 1.0000x reference)
//
#include <hip/hip_runtime.h>
#include <math.h>

#define BB 16
#define SS 64
#define NN 128
#define FF 16
#define HH 64
#define EE 1024
#define ET 1152   // EE + NN self-loops
#define LLAYERS 2
#define XPAD 65   // padded LDS row stride for xl/xr (bank = (s+h)%32)
#define RT (BB * SS * NN)   // 131072 GRU input rows

__device__ __forceinline__ float readlane_f(float v, int k) {
  return __int_as_float(__builtin_amdgcn_readlane(__float_as_int(v), k));
}
// monotonic float<->uint mapping for atomicMax-based float max
__device__ __forceinline__ unsigned flipf(float f) {
  unsigned u = __float_as_uint(f);
  unsigned mask = (u & 0x80000000u) ? 0xFFFFFFFFu : 0x80000000u;
  return u ^ mask;
}
__device__ __forceinline__ float unflipf(unsigned u) {
  unsigned b = (u & 0x80000000u) ? (u ^ 0x80000000u) : ~u;
  return __uint_as_float(b);
}
__device__ __forceinline__ float sigmoidf_(float x) { return 1.f / (1.f + expf(-x)); }

// ---------------- CSR setup (graph is identical for every (b,s)) -------------
__global__ void setup_csr_kernel(const int* __restrict__ ei,
                                 int* __restrict__ off,
                                 int* __restrict__ csrc,
                                 int* __restrict__ ctgt) {
  __shared__ int deg[NN], cur[NN], offs[NN + 1];
  int tid = threadIdx.x;
  if (tid < NN) deg[tid] = 0;
  __syncthreads();
  for (int e = tid; e < ET; e += 256) {
    int tg = (e < EE) ? ei[EE + e] : (e - EE);
    atomicAdd(&deg[tg], 1);
  }
  __syncthreads();
  if (tid == 0) {
    int s = 0;
    for (int i = 0; i < NN; ++i) { offs[i] = s; s += deg[i]; }
    offs[NN] = s;
  }
  __syncthreads();
  if (tid < NN) cur[tid] = offs[tid];
  if (tid <= NN) off[tid] = offs[tid];
  __syncthreads();
  for (int e = tid; e < ET; e += 256) {
    int sv, tg;
    if (e < EE) { sv = ei[e]; tg = ei[EE + e]; }
    else        { sv = e - EE; tg = e - EE; }
    int pos = atomicAdd(&cur[tg], 1);
    csrc[pos] = sv;
    ctgt[pos] = tg;
  }
}

// ---------------- input projection: h = x @ W^T + b --------------------------
__global__ __launch_bounds__(256) void input_proj_kernel(
    const float* __restrict__ x, const float* __restrict__ W,
    const float* __restrict__ bvec, float* __restrict__ h) {
  int lane = threadIdx.x & 63;
  int wid = threadIdx.x >> 6;
  float wreg[FF];
#pragma unroll
  for (int i = 0; i < FF / 4; ++i)
    *(float4*)&wreg[4 * i] = ((const float4*)(W + lane * FF))[i];
  float bias = bvec[lane];
  int row0 = __builtin_amdgcn_readfirstlane((blockIdx.x * 4 + wid) * 32);
#pragma unroll 2
  for (int r = 0; r < 32; ++r) {
    int row = row0 + r;
    const float* xr = x + row * FF;
    float acc = bias;
#pragma unroll
    for (int f = 0; f < FF; ++f) acc += xr[f] * wreg[f];
    h[row * HH + lane] = acc;
  }
}

// ---------------- GAT kernel A: xl = h@Wl^T+bl, xr = h@Wr^T+br ---------------
// R4: 1-wave blocks, lane j owns output col j of BOTH Wl and Wr (128 weight
// floats register-resident under the (64,2) 256-VGPR budget). Block stages
// its 64 h rows (16 KB) into LDS with coalesced float4 loads; the matvec
// operand comes from uniform ds_read_b128 broadcasts (conflict-free) instead
// of the old wave-uniform scalar-path global loads (33 MB stream missing the
// scalar cache = the measured 44%-VALUBusy latency wall in gi_proj/xlxr).
// Stores: lane-contiguous 256 B per row -> fully coalesced.
__global__ __launch_bounds__(64, 2) void xlxr_kernel(
    const float* __restrict__ hin,
    const float* __restrict__ Wl, const float* __restrict__ bl,
    const float* __restrict__ Wr, const float* __restrict__ br,
    float* __restrict__ xl, float* __restrict__ xr) {
  __shared__ float hsh[64][HH];        // 16 KB: 64 staged h rows
  int j = threadIdx.x;                 // output column 0..63
  float wl_[HH], wr_[HH];
  {
    const float4* sl = (const float4*)(Wl + (size_t)j * HH);
    const float4* sr = (const float4*)(Wr + (size_t)j * HH);
#pragma unroll
    for (int i = 0; i < HH / 4; ++i) {
      *(float4*)&wl_[4 * i] = sl[i];
      *(float4*)&wr_[4 * i] = sr[i];
    }
  }
  float blj = bl[j], brj = br[j];
  int row0 = blockIdx.x * 64;
  {
    const float4* src = (const float4*)(hin + (size_t)row0 * HH);
    float4* dst = (float4*)hsh;
#pragma unroll
    for (int i = 0; i < 16; ++i)
      dst[i * 64 + j] = src[i * 64 + j];   // coalesced 1 KB per instr
  }
  __syncthreads();
#pragma unroll 2
  for (int r = 0; r < 64; ++r) {
    float al0 = blj, al1 = 0.f, ar0 = brj, ar1 = 0.f;
#pragma unroll
    for (int k = 0; k < HH; k += 4) {
      float4 hb = *(const float4*)&hsh[r][k];    // uniform broadcast read
      al0 += hb.x * wl_[k + 0]; ar0 += hb.x * wr_[k + 0];
      al1 += hb.y * wl_[k + 1]; ar1 += hb.y * wr_[k + 1];
      al0 += hb.z * wl_[k + 2]; ar0 += hb.z * wr_[k + 2];
      al1 += hb.w * wl_[k + 3]; ar1 += hb.w * wr_[k + 3];
    }
    size_t o = (size_t)(row0 + r) * HH + j;
    xl[o] = al0 + al1;                  // 256 B coalesced store
    xr[o] = ar0 + ar1;
  }
}

// ---------------- GAT kernel B: edge logits + softmax + aggregate ------------
__global__ __launch_bounds__(256) void gat_edge_kernel(
    const float* __restrict__ xl_g, const float* __restrict__ xr_g,
    float* __restrict__ hout,
    const int* __restrict__ csr_off, const int* __restrict__ csr_src,
    const int* __restrict__ csr_tgt,
    const float* __restrict__ att, const float* __restrict__ bo) {
  __shared__ float xl_sh[NN * XPAD];   // 33.3 KB
  __shared__ float xr_sh[NN * XPAD];   // 33.3 KB
  __shared__ float p_sh[ET];
  __shared__ int st_sh[ET];
  __shared__ unsigned m_sh[NN];
  int tid = threadIdx.x, lane = tid & 63, wid = tid >> 6;
  int base = blockIdx.x * (NN * HH);

  // stage xl/xr with padded stride
#pragma unroll 1
  for (int i = tid * 4; i < NN * HH; i += 256 * 4) {
    int row = i >> 6, h = i & 63;
    float4 vl = *(const float4*)(xl_g + base + i);
    float4 vr = *(const float4*)(xr_g + base + i);
    float* dl = xl_sh + row * XPAD + h;
    float* dr = xr_sh + row * XPAD + h;
    dl[0] = vl.x; dl[1] = vl.y; dl[2] = vl.z; dl[3] = vl.w;
    dr[0] = vr.x; dr[1] = vr.y; dr[2] = vr.z; dr[3] = vr.w;
  }
  for (int i = tid; i < ET; i += 256)
    st_sh[i] = csr_src[i] | (csr_tgt[i] << 16);
  if (tid < NN) m_sh[tid] = 0u;
  __syncthreads();

  // pass 1: thread-per-edge attention logit + segment max
#pragma unroll 1
  for (int e = tid; e < ET; e += 256) {
    int st = st_sh[e];
    int s = st & 0xffff, tg = st >> 16;
    const float* xlr = xl_sh + s * XPAD;
    const float* xrr = xr_sh + tg * XPAD;
    float a0 = 0.f, a1 = 0.f, a2 = 0.f, a3 = 0.f;
#pragma unroll
    for (int h = 0; h < HH; h += 4) {
      float v0 = xlr[h + 0] + xrr[h + 0]; v0 = (v0 > 0.f) ? v0 : 0.2f * v0;
      float v1 = xlr[h + 1] + xrr[h + 1]; v1 = (v1 > 0.f) ? v1 : 0.2f * v1;
      float v2 = xlr[h + 2] + xrr[h + 2]; v2 = (v2 > 0.f) ? v2 : 0.2f * v2;
      float v3 = xlr[h + 3] + xrr[h + 3]; v3 = (v3 > 0.f) ? v3 : 0.2f * v3;
      a0 += v0 * att[h + 0];
      a1 += v1 * att[h + 1];
      a2 += v2 * att[h + 2];
      a3 += v3 * att[h + 3];
    }
    float a = (a0 + a1) + (a2 + a3);
    p_sh[e] = a;
    atomicMax(&m_sh[tg], flipf(a));
  }
  __syncthreads();

  // pass 2: stabilized exp
  for (int e = tid; e < ET; e += 256) {
    int tg = st_sh[e] >> 16;
    p_sh[e] = expf(p_sh[e] - unflipf(m_sh[tg]));
  }
  __syncthreads();

  // gather: wave per target node, CSR-contiguous edge segment
  float bo_l = bo[lane];
#pragma unroll 1
  for (int n = wid; n < NN; n += 4) {
    int o0 = __builtin_amdgcn_readfirstlane(csr_off[n]);
    int o1 = __builtin_amdgcn_readfirstlane(csr_off[n + 1]);
    float acc = 0.f, z = 0.f;
    for (int i = o0; i < o1; ++i) {
      float p = p_sh[i];
      int s = st_sh[i] & 0xffff;
      acc += p * xl_sh[s * XPAD + lane];
      z += p;
    }
    float o = acc / z + bo_l;
    hout[base + n * HH + lane] = fmaxf(o, 0.f);
  }
}

// ---------------- fallback fused GAT (used if ws too small) ------------------
__device__ __forceinline__ void gemm_half(
    const float* __restrict__ hin, int base,
    const float* __restrict__ W, const float* __restrict__ bvec,
    float* __restrict__ out_sh, int half, int lane) {
  float wreg[HH];
#pragma unroll
  for (int i = 0; i < HH / 4; ++i)
    *(float4*)&wreg[4 * i] = ((const float4*)(W + lane * HH))[i];
  float bias = bvec[lane];
  int n0 = __builtin_amdgcn_readfirstlane(half * 64);
#pragma unroll 1
  for (int nd = 0; nd < 64; ++nd) {
    int node = n0 + nd;
    const float* hrow = hin + base + node * HH;
    float a0 = bias, a1 = 0.f, a2 = 0.f, a3 = 0.f;
#pragma unroll
    for (int f = 0; f < HH; f += 4) {
      a0 += hrow[f + 0] * wreg[f + 0];
      a1 += hrow[f + 1] * wreg[f + 1];
      a2 += hrow[f + 2] * wreg[f + 2];
      a3 += hrow[f + 3] * wreg[f + 3];
    }
    out_sh[node * HH + lane] = (a0 + a1) + (a2 + a3);
  }
}

__global__ __launch_bounds__(256) void gat_fused_kernel(
    const float* __restrict__ hin, float* __restrict__ hout,
    const int* __restrict__ csr_off, const int* __restrict__ csr_src,
    const int* __restrict__ csr_tgt,
    const float* __restrict__ Wl, const float* __restrict__ bl,
    const float* __restrict__ Wr, const float* __restrict__ br,
    const float* __restrict__ att, const float* __restrict__ bo) {
  __shared__ float xl_sh[NN * HH];
  __shared__ float xr_sh[NN * HH];
  __shared__ float p_sh[ET];
  __shared__ int st_sh[ET];
  __shared__ unsigned m_sh[NN];
  int tid = threadIdx.x, lane = tid & 63, wid = tid >> 6;
  int base = blockIdx.x * (NN * HH);

  for (int i = tid; i < ET; i += 256)
    st_sh[i] = csr_src[i] | (csr_tgt[i] << 16);
  if (tid < NN) m_sh[tid] = 0u;

  if (wid < 2) gemm_half(hin, base, Wl, bl, xl_sh, wid & 1, lane);
  else         gemm_half(hin, base, Wr, br, xr_sh, wid & 1, lane);

  float att_l = att[lane];
  float bo_l = bo[lane];
  __syncthreads();

#pragma unroll 1
  for (int e = wid; e < ET; e += 4) {
    int st = st_sh[e];
    int s = st & 0xffff, tg = st >> 16;
    float v = xl_sh[s * HH + lane] + xr_sh[tg * HH + lane];
    v = (v > 0.f) ? v : 0.2f * v;
    float prod = v * att_l;
#pragma unroll
    for (int mm = 32; mm; mm >>= 1) prod += __shfl_xor(prod, mm);
    if (lane == 0) {
      p_sh[e] = prod;
      atomicMax(&m_sh[tg], flipf(prod));
    }
  }
  __syncthreads();

  for (int e = tid; e < ET; e += 256) {
    int tg = st_sh[e] >> 16;
    p_sh[e] = expf(p_sh[e] - unflipf(m_sh[tg]));
  }
  __syncthreads();

#pragma unroll 1
  for (int n = wid; n < NN; n += 4) {
    int o0 = csr_off[n], o1 = csr_off[n + 1];
    float acc = 0.f, z = 0.f;
    for (int i = o0; i < o1; ++i) {
      float p = p_sh[i];
      int s = st_sh[i] & 0xffff;
      acc += p * xl_sh[s * HH + lane];
      z += p;
    }
    float o = acc / z + bo_l;
    hout[base + n * HH + lane] = fmaxf(o, 0.f);
  }
}

// ---------------- GRU stage A: gi = hbuf @ Wih^T + bih  (batched GEMM) -------
// R4: same LDS-broadcast restructure as xlxr. 1-wave blocks, lane j owns
// output col j of ALL THREE gates (192 weight floats; (64,2) gives the
// 256-VGPR budget gru_rec already proved sufficient for 192-float arrays).
// 64 h rows staged coalesced into LDS once, then uniform ds_read_b128
// broadcasts feed 12 FMAs each -> VALU-bound by construction. Stores are
// three 256 B coalesced dword stores per row.
__global__ __launch_bounds__(64, 2) void gi_proj_kernel(
    const float* __restrict__ hin, const float* __restrict__ Wih,
    const float* __restrict__ bih, float* __restrict__ gi) {
  __shared__ float hsh[64][HH];        // 16 KB
  int j = threadIdx.x;                 // output column 0..63
  float wr[HH], wz[HH], wn[HH];
  {
    const float4* s0 = (const float4*)(Wih + (size_t)(0 * 64 + j) * HH);
    const float4* s1 = (const float4*)(Wih + (size_t)(1 * 64 + j) * HH);
    const float4* s2 = (const float4*)(Wih + (size_t)(2 * 64 + j) * HH);
#pragma unroll
    for (int i = 0; i < HH / 4; ++i) {
      *(float4*)&wr[4 * i] = s0[i];
      *(float4*)&wz[4 * i] = s1[i];
      *(float4*)&wn[4 * i] = s2[i];
    }
  }
  float br_ = bih[j], bz_ = bih[64 + j], bn_ = bih[128 + j];
  int row0 = blockIdx.x * 64;
  {
    const float4* src = (const float4*)(hin + (size_t)row0 * HH);
    float4* dst = (float4*)hsh;
#pragma unroll
    for (int i = 0; i < 16; ++i)
      dst[i * 64 + j] = src[i * 64 + j];   // coalesced 1 KB per instr
  }
  __syncthreads();
#pragma unroll 2
  for (int r = 0; r < 64; ++r) {
    float ar0 = br_, ar1 = 0.f, az0 = bz_, az1 = 0.f, an0 = bn_, an1 = 0.f;
#pragma unroll
    for (int k = 0; k < HH; k += 4) {
      float4 hb = *(const float4*)&hsh[r][k];    // uniform broadcast read
      ar0 += hb.x * wr[k + 0]; az0 += hb.x * wz[k + 0]; an0 += hb.x * wn[k + 0];
      ar1 += hb.y * wr[k + 1]; az1 += hb.y * wz[k + 1]; an1 += hb.y * wn[k + 1];
      ar0 += hb.z * wr[k + 2]; az0 += hb.z * wz[k + 2]; an0 += hb.z * wn[k + 2];
      ar1 += hb.w * wr[k + 3]; az1 += hb.w * wz[k + 3]; an1 += hb.w * wn[k + 3];
    }
    size_t o = (size_t)(row0 + r) * 192;
    gi[o + j]       = ar0 + ar1;         // 3x 256 B coalesced stores
    gi[o + 64 + j]  = az0 + az1;
    gi[o + 128 + j] = an0 + an1;
  }
}

// ---------------- GRU stage B: recurrence, one wave per sequence -------------
// 2048 blocks x 64 threads; zero cross-wave traffic. Lane j holds Whh rows
// {j, 64+j, 128+j} (192 floats, (64,2) -> 256-reg budget, no spill).
// R4: h broadcast via 256 B LDS hsh + uniform float4 reads (replaces the 64
// v_readlane/step VALU+SGPR-hazard chains). gi streamed from global with
// depth-2 prefetch. 2048 waves = chip-resident in one round.
__global__ __launch_bounds__(64, 2) void gru_rec_kernel(
    const float* __restrict__ gi,
    const float* __restrict__ Whh, const float* __restrict__ bhh,
    const float* __restrict__ oW1, const float* __restrict__ ob1,
    const float* __restrict__ oW2, const float* __restrict__ ob2,
    const float* __restrict__ dW1, const float* __restrict__ db1,
    const float* __restrict__ dW2, const float* __restrict__ db2,
    float* __restrict__ out) {
  __shared__ float hsh[HH];                    // 256 B h broadcast buffer
  int lane = threadIdx.x;                      // 0..63
  int seq = blockIdx.x;                        // b*N + n
  int b = seq >> 7, n = seq & (NN - 1);

  float wr[HH], wz[HH], wn[HH];
  {
    const float4* s0 = (const float4*)(Whh + (size_t)(0 * 64 + lane) * HH);
    const float4* s1 = (const float4*)(Whh + (size_t)(1 * 64 + lane) * HH);
    const float4* s2 = (const float4*)(Whh + (size_t)(2 * 64 + lane) * HH);
#pragma unroll
    for (int i = 0; i < HH / 4; ++i) {
      *(float4*)&wr[4 * i] = s0[i];
      *(float4*)&wz[4 * i] = s1[i];
      *(float4*)&wn[4 * i] = s2[i];
    }
  }
  float br_ = bhh[lane], bz_ = bhh[64 + lane], bn_ = bhh[128 + lane];

  const float* gbase = gi + ((size_t)b * SS * NN + (size_t)n) * 192;  // +t*NN*192
  // depth-2 software pipeline on gi loads
  float gir = gbase[lane], giz = gbase[64 + lane], gin = gbase[128 + lane];
  const float* g1 = gbase + (size_t)NN * 192;
  float pir = g1[lane], piz = g1[64 + lane], pin = g1[128 + lane];
  float hj = 0.f;
  hsh[lane] = 0.f;
  __syncthreads();

#pragma unroll 1
  for (int t = 0; t < SS; ++t) {
    float qir = 0.f, qiz = 0.f, qin = 0.f;
    if (t + 2 < SS) {
      const float* g2 = gbase + (size_t)(t + 2) * NN * 192;
      qir = g2[lane]; qiz = g2[64 + lane]; qin = g2[128 + lane];
    }
    float ar0 = br_, ar1 = 0.f, az0 = bz_, az1 = 0.f, an0 = bn_, an1 = 0.f;
#pragma unroll
    for (int k = 0; k < HH; k += 4) {
      float4 hb = *(const float4*)(hsh + k);   // uniform broadcast read
      ar0 += hb.x * wr[k + 0]; az0 += hb.x * wz[k + 0]; an0 += hb.x * wn[k + 0];
      ar1 += hb.y * wr[k + 1]; az1 += hb.y * wz[k + 1]; an1 += hb.y * wn[k + 1];
      ar0 += hb.z * wr[k + 2]; az0 += hb.z * wz[k + 2]; an0 += hb.z * wn[k + 2];
      ar1 += hb.w * wr[k + 3]; az1 += hb.w * wz[k + 3]; an1 += hb.w * wn[k + 3];
    }
    float r  = sigmoidf_(gir + ar0 + ar1);
    float z  = sigmoidf_(giz + az0 + az1);
    float nn_ = tanhf(gin + r * (an0 + an1));
    hj = (1.f - z) * nn_ + z * hj;
    hsh[lane] = hj;                            // reads of this step already
    __syncthreads();                           // retired (hb consumed above)
    gir = pir; giz = piz; gin = pin;
    pir = qir; piz = qiz; pin = qin;
  }

  // ---- fused heads: lanes 0..31 = order head, 32..63 = demand head ----
  int half = lane >> 5, jp = lane & 31;
  const float* W1 = half ? dW1 : oW1;
  const float* b1 = half ? db1 : ob1;
  const float* W2 = half ? dW2 : oW2;
  const float* b2 = half ? db2 : ob2;
  float wv[HH];
#pragma unroll
  for (int i = 0; i < HH / 4; ++i)
    *(float4*)&wv[4 * i] = ((const float4*)(W1 + jp * HH))[i];
  float acc = b1[jp];
#pragma unroll
  for (int k = 0; k < HH; k += 4) {
    float4 hb = *(const float4*)(hsh + k);     // final h broadcast
    acc += hb.x * wv[k + 0];
    acc += hb.y * wv[k + 1];
    acc += hb.z * wv[k + 2];
    acc += hb.w * wv[k + 3];
  }
  float val = fmaxf(acc, 0.f) * W2[jp];
  val += __shfl_down(val, 16, 32);
  val += __shfl_down(val, 8, 32);
  val += __shfl_down(val, 4, 32);
  val += __shfl_down(val, 2, 32);
  val += __shfl_down(val, 1, 32);
  if (jp == 0) out[half * (BB * NN) + seq] = val + b2[0];
}

// ---------------- fallback GRU (used if ws too small for gi) -----------------
__global__ __launch_bounds__(192, 3) void gru_fused_kernel(
    const float* __restrict__ hbuf,
    const float* __restrict__ Wih, const float* __restrict__ Whh,
    const float* __restrict__ bih, const float* __restrict__ bhh,
    const float* __restrict__ oW1, const float* __restrict__ ob1,
    const float* __restrict__ oW2, const float* __restrict__ ob2,
    const float* __restrict__ dW1, const float* __restrict__ db1,
    const float* __restrict__ dW2, const float* __restrict__ db2,
    float* __restrict__ out) {
  __shared__ float gi_sh[SS * 3 * HH];   // 48 KB  [t][gate][j]
  __shared__ float exch[2][3][HH];       // double-buffered gh exchange

  int lane = threadIdx.x & 63;
  int g = (int)threadIdx.x >> 6;
  int seq = blockIdx.x;
  int b = seq >> 7, n = seq & (NN - 1);
  const float* xbase = hbuf + ((size_t)b * SS * NN + (size_t)n) * HH;

  {
    float w[HH];
    const float4* wsrc = (const float4*)(Wih + (size_t)(g * 64 + lane) * HH);
#pragma unroll
    for (int i = 0; i < HH / 4; ++i) *(float4*)&w[4 * i] = wsrc[i];
    float bias = bih[g * 64 + lane];
#pragma unroll 2
    for (int t = 0; t < SS; ++t) {
      const float* xr = xbase + (size_t)t * NN * HH;
      float a0 = bias, a1 = 0.f, a2 = 0.f, a3 = 0.f;
#pragma unroll
      for (int k = 0; k < HH; k += 4) {
        float4 xb = *(const float4*)(xr + k);
        a0 += xb.x * w[k + 0];
        a1 += xb.y * w[k + 1];
        a2 += xb.z * w[k + 2];
        a3 += xb.w * w[k + 3];
      }
      gi_sh[(t * 3 + g) * HH + lane] = (a0 + a1) + (a2 + a3);
    }
  }

  float whh[HH];
  {
    const float4* wsrc = (const float4*)(Whh + (size_t)(g * 64 + lane) * HH);
#pragma unroll
    for (int i = 0; i < HH / 4; ++i) *(float4*)&whh[4 * i] = wsrc[i];
  }
  float bhg = bhh[g * 64 + lane];
  float hj = 0.f;
  __syncthreads();

#pragma unroll 1
  for (int t = 0; t < SS; ++t) {
    float a0 = bhg, a1 = 0.f, a2 = 0.f, a3 = 0.f;
#pragma unroll
    for (int k = 0; k < HH; k += 4) {
      a0 += readlane_f(hj, k + 0) * whh[k + 0];
      a1 += readlane_f(hj, k + 1) * whh[k + 1];
      a2 += readlane_f(hj, k + 2) * whh[k + 2];
      a3 += readlane_f(hj, k + 3) * whh[k + 3];
    }
    float gh = (a0 + a1) + (a2 + a3);
    int slot = t & 1;
    exch[slot][g][lane] = gh;
    __syncthreads();
    float ghr = exch[slot][0][lane];
    float ghz = exch[slot][1][lane];
    float ghn = exch[slot][2][lane];
    float gir = gi_sh[(t * 3 + 0) * HH + lane];
    float giz = gi_sh[(t * 3 + 1) * HH + lane];
    float gin = gi_sh[(t * 3 + 2) * HH + lane];
    float r  = sigmoidf_(gir + ghr);
    float z  = sigmoidf_(giz + ghz);
    float nn_ = tanhf(gin + r * ghn);
    hj = (1.f - z) * nn_ + z * hj;
  }

  if (g == 0) {
    int half = lane >> 5, jp = lane & 31;
    const float* W1 = half ? dW1 : oW1;
    const float* b1 = half ? db1 : ob1;
    const float* W2 = half ? dW2 : oW2;
    const float* b2 = half ? db2 : ob2;
    float wv[HH];
#pragma unroll
    for (int i = 0; i < HH / 4; ++i)
      *(float4*)&wv[4 * i] = ((const float4*)(W1 + jp * HH))[i];
    float acc = b1[jp];
#pragma unroll
    for (int k = 0; k < HH; ++k)
      acc += readlane_f(hj, k) * wv[k];
    float val = fmaxf(acc, 0.f) * W2[jp];
    val += __shfl_down(val, 16, 32);
    val += __shfl_down(val, 8, 32);
    val += __shfl_down(val, 4, 32);
    val += __shfl_down(val, 2, 32);
    val += __shfl_down(val, 1, 32);
    if (jp == 0) out[half * (BB * NN) + seq] = val + b2[0];
  }
}

// ---------------- launch -----------------------------------------------------
extern "C" void kernel_launch(void* const* d_in, const int* in_sizes, int n_in,
                              void* d_out, int out_size, void* d_ws, size_t ws_size,
                              hipStream_t stream) {
  const float* x       = (const float*)d_in[0];
  const int*   ei      = (const int*)d_in[1];
  const float* in_W    = (const float*)d_in[2];
  const float* in_b    = (const float*)d_in[3];
  const float* gat_Wl  = (const float*)d_in[4];
  const float* gat_bl  = (const float*)d_in[5];
  const float* gat_Wr  = (const float*)d_in[6];
  const float* gat_br  = (const float*)d_in[7];
  const float* gat_att = (const float*)d_in[8];
  const float* gat_bias= (const float*)d_in[9];
  const float* gru_Wih = (const float*)d_in[10];
  const float* gru_Whh = (const float*)d_in[11];
  const float* gru_bih = (const float*)d_in[12];
  const float* gru_bhh = (const float*)d_in[13];
  const float* oh_W1   = (const float*)d_in[14];
  const float* oh_b1   = (const float*)d_in[15];
  const float* oh_W2   = (const float*)d_in[16];
  const float* oh_b2   = (const float*)d_in[17];
  const float* dh_W1   = (const float*)d_in[18];
  const float* dh_b1   = (const float*)d_in[19];
  const float* dh_W2   = (const float*)d_in[20];
  const float* dh_b2   = (const float*)d_in[21];
  float* out = (float*)d_out;

  char* ws = (char*)d_ws;
  size_t hfloats = (size_t)BB * SS * NN * HH;           // 8.39M floats
  float* hbuf = (float*)ws;
  size_t off_csr = hfloats * sizeof(float);
  size_t off_buf = off_csr + (160 + 2 * ET) * sizeof(int);
  off_buf = (off_buf + 255) & ~(size_t)255;             // 256B align
  int* csr_off = (int*)(ws + off_csr);
  int* csr_src = csr_off + 160;
  int* csr_tgt = csr_src + ET;
  float* xlbuf = (float*)(ws + off_buf);
  float* xrbuf = xlbuf + hfloats;
  size_t need_gat = off_buf + 2 * hfloats * sizeof(float);
  bool big_gat = (ws_size >= need_gat);
  // gi buffer overlays xl/xr (dead after the GAT layers): RT*192 floats
  float* gibuf = (float*)(ws + off_buf);
  size_t need_gru = off_buf + (size_t)RT * 192 * sizeof(float);  // ~134 MB
  bool big_gru = (ws_size >= need_gru);

  setup_csr_kernel<<<1, 256, 0, stream>>>(ei, csr_off, csr_src, csr_tgt);
  input_proj_kernel<<<(BB * SS * NN) / (4 * 32), 256, 0, stream>>>(x, in_W, in_b, hbuf);
  for (int l = 0; l < LLAYERS; ++l) {
    if (big_gat) {
      xlxr_kernel<<<RT / 64, 64, 0, stream>>>(
          hbuf, gat_Wl + l * HH * HH, gat_bl + l * HH,
          gat_Wr + l * HH * HH, gat_br + l * HH, xlbuf, xrbuf);
      gat_edge_kernel<<<BB * SS, 256, 0, stream>>>(
          xlbuf, xrbuf, hbuf, csr_off, csr_src, csr_tgt,
          gat_att + l * HH, gat_bias + l * HH);
    } else {
      gat_fused_kernel<<<BB * SS, 256, 0, stream>>>(
          hbuf, hbuf, csr_off, csr_src, csr_tgt,
          gat_Wl + l * HH * HH, gat_bl + l * HH,
          gat_Wr + l * HH * HH, gat_br + l * HH,
          gat_att + l * HH, gat_bias + l * HH);
    }
  }
  if (big_gru) {
    gi_proj_kernel<<<RT / 64, 64, 0, stream>>>(hbuf, gru_Wih, gru_bih, gibuf);
    gru_rec_kernel<<<BB * NN, 64, 0, stream>>>(
        gibuf, gru_Whh, gru_bhh,
        oh_W1, oh_b1, oh_W2, oh_b2, dh_W1, dh_b1, dh_W2, dh_b2, out);
  } else {
    gru_fused_kernel<<<BB * NN, 192, 0, stream>>>(
        hbuf, gru_Wih, gru_Whh, gru_bih, gru_bhh,
        oh_W1, oh_b1, oh_W2, oh_b2, dh_W1, dh_b1, dh_W2, dh_b2, out);
  }
}

// Round 5
// 1771.933 us; speedup vs baseline: 1.0008x; 1.0008x over previous
//
#include <hip/hip_runtime.h>
#include <math.h>

#define BB 16
#define SS 64
#define NN 128
#define FF 16
#define HH 64
#define EE 1024
#define ET 1152   // EE + NN self-loops
#define LLAYERS 2
#define XPAD 65   // padded LDS row stride for xl/xr (bank = (s+h)%32)
#define RT (BB * SS * NN)   // 131072 GRU input rows

__device__ __forceinline__ float readlane_f(float v, int k) {
  return __int_as_float(__builtin_amdgcn_readlane(__float_as_int(v), k));
}
// monotonic float<->uint mapping for atomicMax-based float max
__device__ __forceinline__ unsigned flipf(float f) {
  unsigned u = __float_as_uint(f);
  unsigned mask = (u & 0x80000000u) ? 0xFFFFFFFFu : 0x80000000u;
  return u ^ mask;
}
__device__ __forceinline__ float unflipf(unsigned u) {
  unsigned b = (u & 0x80000000u) ? (u ^ 0x80000000u) : ~u;
  return __uint_as_float(b);
}
__device__ __forceinline__ float sigmoidf_(float x) { return 1.f / (1.f + expf(-x)); }

// ---------------- CSR setup (graph is identical for every (b,s)) -------------
__global__ void setup_csr_kernel(const int* __restrict__ ei,
                                 int* __restrict__ off,
                                 int* __restrict__ csrc,
                                 int* __restrict__ ctgt) {
  __shared__ int deg[NN], cur[NN], offs[NN + 1];
  int tid = threadIdx.x;
  if (tid < NN) deg[tid] = 0;
  __syncthreads();
  for (int e = tid; e < ET; e += 256) {
    int tg = (e < EE) ? ei[EE + e] : (e - EE);
    atomicAdd(&deg[tg], 1);
  }
  __syncthreads();
  if (tid == 0) {
    int s = 0;
    for (int i = 0; i < NN; ++i) { offs[i] = s; s += deg[i]; }
    offs[NN] = s;
  }
  __syncthreads();
  if (tid < NN) cur[tid] = offs[tid];
  if (tid <= NN) off[tid] = offs[tid];
  __syncthreads();
  for (int e = tid; e < ET; e += 256) {
    int sv, tg;
    if (e < EE) { sv = ei[e]; tg = ei[EE + e]; }
    else        { sv = e - EE; tg = e - EE; }
    int pos = atomicAdd(&cur[tg], 1);
    csrc[pos] = sv;
    ctgt[pos] = tg;
  }
}

// ---------------- input projection: h = x @ W^T + b --------------------------
__global__ __launch_bounds__(256) void input_proj_kernel(
    const float* __restrict__ x, const float* __restrict__ W,
    const float* __restrict__ bvec, float* __restrict__ h) {
  int lane = threadIdx.x & 63;
  int wid = threadIdx.x >> 6;
  float wreg[FF];
#pragma unroll
  for (int i = 0; i < FF / 4; ++i)
    *(float4*)&wreg[4 * i] = ((const float4*)(W + lane * FF))[i];
  float bias = bvec[lane];
  int row0 = __builtin_amdgcn_readfirstlane((blockIdx.x * 4 + wid) * 32);
#pragma unroll 2
  for (int r = 0; r < 32; ++r) {
    int row = row0 + r;
    const float* xr = x + row * FF;
    float acc = bias;
#pragma unroll
    for (int f = 0; f < FF; ++f) acc += xr[f] * wreg[f];
    h[row * HH + lane] = acc;
  }
}

// ---------------- GAT kernel A: xl = h@Wl^T+bl, xr = h@Wr^T+br ---------------
// R5: LDS-broadcast GEMM, spill-proofed. amdgpu_waves_per_eu(2,2) pins the
// occupancy target so the allocator grants the ~150 VGPRs this needs instead
// of capping at 128 and scratch-bouncing (R4's 1.5 GB FETCH disaster).
// Pressure peaks serialized: stage (unroll 4, <=16 regs in flight) -> barrier
// -> weight loads -> row loop (unroll 1).
__global__ __launch_bounds__(64)
__attribute__((amdgpu_waves_per_eu(2, 2)))
void xlxr_kernel(
    const float* __restrict__ hin,
    const float* __restrict__ Wl, const float* __restrict__ bl,
    const float* __restrict__ Wr, const float* __restrict__ br,
    float* __restrict__ xl, float* __restrict__ xr) {
  __shared__ float hsh[64 * HH];       // 16 KB: 64 staged h rows
  int j = threadIdx.x;                 // output column 0..63
  int row0 = blockIdx.x * 64;
  {
    const float4* src4 = (const float4*)(hin + (size_t)row0 * HH);
    float4* dst4 = (float4*)hsh;
#pragma unroll 4
    for (int i = 0; i < 16; ++i)
      dst4[i * 64 + j] = src4[i * 64 + j];   // coalesced 1 KB per instr
  }
  __syncthreads();
  float wl_[HH], wr_[HH];
  {
    const float4* sl = (const float4*)(Wl + (size_t)j * HH);
    const float4* sr = (const float4*)(Wr + (size_t)j * HH);
#pragma unroll
    for (int i = 0; i < HH / 4; ++i) {
      *(float4*)&wl_[4 * i] = sl[i];
      *(float4*)&wr_[4 * i] = sr[i];
    }
  }
  float blj = bl[j], brj = br[j];
#pragma unroll 1
  for (int r = 0; r < 64; ++r) {
    float al0 = blj, al1 = 0.f, ar0 = brj, ar1 = 0.f;
#pragma unroll
    for (int k = 0; k < HH; k += 4) {
      float4 hb = *(const float4*)&hsh[r * HH + k];   // uniform broadcast read
      al0 += hb.x * wl_[k + 0]; ar0 += hb.x * wr_[k + 0];
      al1 += hb.y * wl_[k + 1]; ar1 += hb.y * wr_[k + 1];
      al0 += hb.z * wl_[k + 2]; ar0 += hb.z * wr_[k + 2];
      al1 += hb.w * wl_[k + 3]; ar1 += hb.w * wr_[k + 3];
    }
    size_t o = (size_t)(row0 + r) * HH + j;
    xl[o] = al0 + al1;                  // 256 B coalesced store
    xr[o] = ar0 + ar1;
  }
}

// ---------------- GAT kernel B: edge logits + softmax + aggregate ------------
__global__ __launch_bounds__(256) void gat_edge_kernel(
    const float* __restrict__ xl_g, const float* __restrict__ xr_g,
    float* __restrict__ hout,
    const int* __restrict__ csr_off, const int* __restrict__ csr_src,
    const int* __restrict__ csr_tgt,
    const float* __restrict__ att, const float* __restrict__ bo) {
  __shared__ float xl_sh[NN * XPAD];   // 33.3 KB
  __shared__ float xr_sh[NN * XPAD];   // 33.3 KB
  __shared__ float p_sh[ET];
  __shared__ int st_sh[ET];
  __shared__ unsigned m_sh[NN];
  int tid = threadIdx.x, lane = tid & 63, wid = tid >> 6;
  int base = blockIdx.x * (NN * HH);

  // stage xl/xr with padded stride
#pragma unroll 1
  for (int i = tid * 4; i < NN * HH; i += 256 * 4) {
    int row = i >> 6, h = i & 63;
    float4 vl = *(const float4*)(xl_g + base + i);
    float4 vr = *(const float4*)(xr_g + base + i);
    float* dl = xl_sh + row * XPAD + h;
    float* dr = xr_sh + row * XPAD + h;
    dl[0] = vl.x; dl[1] = vl.y; dl[2] = vl.z; dl[3] = vl.w;
    dr[0] = vr.x; dr[1] = vr.y; dr[2] = vr.z; dr[3] = vr.w;
  }
  for (int i = tid; i < ET; i += 256)
    st_sh[i] = csr_src[i] | (csr_tgt[i] << 16);
  if (tid < NN) m_sh[tid] = 0u;
  __syncthreads();

  // pass 1: thread-per-edge attention logit + segment max
#pragma unroll 1
  for (int e = tid; e < ET; e += 256) {
    int st = st_sh[e];
    int s = st & 0xffff, tg = st >> 16;
    const float* xlr = xl_sh + s * XPAD;
    const float* xrr = xr_sh + tg * XPAD;
    float a0 = 0.f, a1 = 0.f, a2 = 0.f, a3 = 0.f;
#pragma unroll
    for (int h = 0; h < HH; h += 4) {
      float v0 = xlr[h + 0] + xrr[h + 0]; v0 = (v0 > 0.f) ? v0 : 0.2f * v0;
      float v1 = xlr[h + 1] + xrr[h + 1]; v1 = (v1 > 0.f) ? v1 : 0.2f * v1;
      float v2 = xlr[h + 2] + xrr[h + 2]; v2 = (v2 > 0.f) ? v2 : 0.2f * v2;
      float v3 = xlr[h + 3] + xrr[h + 3]; v3 = (v3 > 0.f) ? v3 : 0.2f * v3;
      a0 += v0 * att[h + 0];
      a1 += v1 * att[h + 1];
      a2 += v2 * att[h + 2];
      a3 += v3 * att[h + 3];
    }
    float a = (a0 + a1) + (a2 + a3);
    p_sh[e] = a;
    atomicMax(&m_sh[tg], flipf(a));
  }
  __syncthreads();

  // pass 2: stabilized exp
  for (int e = tid; e < ET; e += 256) {
    int tg = st_sh[e] >> 16;
    p_sh[e] = expf(p_sh[e] - unflipf(m_sh[tg]));
  }
  __syncthreads();

  // gather: wave per target node, CSR-contiguous edge segment
  float bo_l = bo[lane];
#pragma unroll 1
  for (int n = wid; n < NN; n += 4) {
    int o0 = __builtin_amdgcn_readfirstlane(csr_off[n]);
    int o1 = __builtin_amdgcn_readfirstlane(csr_off[n + 1]);
    float acc = 0.f, z = 0.f;
    for (int i = o0; i < o1; ++i) {
      float p = p_sh[i];
      int s = st_sh[i] & 0xffff;
      acc += p * xl_sh[s * XPAD + lane];
      z += p;
    }
    float o = acc / z + bo_l;
    hout[base + n * HH + lane] = fmaxf(o, 0.f);
  }
}

// ---------------- fallback fused GAT (used if ws too small) ------------------
__device__ __forceinline__ void gemm_half(
    const float* __restrict__ hin, int base,
    const float* __restrict__ W, const float* __restrict__ bvec,
    float* __restrict__ out_sh, int half, int lane) {
  float wreg[HH];
#pragma unroll
  for (int i = 0; i < HH / 4; ++i)
    *(float4*)&wreg[4 * i] = ((const float4*)(W + lane * HH))[i];
  float bias = bvec[lane];
  int n0 = __builtin_amdgcn_readfirstlane(half * 64);
#pragma unroll 1
  for (int nd = 0; nd < 64; ++nd) {
    int node = n0 + nd;
    const float* hrow = hin + base + node * HH;
    float a0 = bias, a1 = 0.f, a2 = 0.f, a3 = 0.f;
#pragma unroll
    for (int f = 0; f < HH; f += 4) {
      a0 += hrow[f + 0] * wreg[f + 0];
      a1 += hrow[f + 1] * wreg[f + 1];
      a2 += hrow[f + 2] * wreg[f + 2];
      a3 += hrow[f + 3] * wreg[f + 3];
    }
    out_sh[node * HH + lane] = (a0 + a1) + (a2 + a3);
  }
}

__global__ __launch_bounds__(256) void gat_fused_kernel(
    const float* __restrict__ hin, float* __restrict__ hout,
    const int* __restrict__ csr_off, const int* __restrict__ csr_src,
    const int* __restrict__ csr_tgt,
    const float* __restrict__ Wl, const float* __restrict__ bl,
    const float* __restrict__ Wr, const float* __restrict__ br,
    const float* __restrict__ att, const float* __restrict__ bo) {
  __shared__ float xl_sh[NN * HH];
  __shared__ float xr_sh[NN * HH];
  __shared__ float p_sh[ET];
  __shared__ int st_sh[ET];
  __shared__ unsigned m_sh[NN];
  int tid = threadIdx.x, lane = tid & 63, wid = tid >> 6;
  int base = blockIdx.x * (NN * HH);

  for (int i = tid; i < ET; i += 256)
    st_sh[i] = csr_src[i] | (csr_tgt[i] << 16);
  if (tid < NN) m_sh[tid] = 0u;

  if (wid < 2) gemm_half(hin, base, Wl, bl, xl_sh, wid & 1, lane);
  else         gemm_half(hin, base, Wr, br, xr_sh, wid & 1, lane);

  float att_l = att[lane];
  float bo_l = bo[lane];
  __syncthreads();

#pragma unroll 1
  for (int e = wid; e < ET; e += 4) {
    int st = st_sh[e];
    int s = st & 0xffff, tg = st >> 16;
    float v = xl_sh[s * HH + lane] + xr_sh[tg * HH + lane];
    v = (v > 0.f) ? v : 0.2f * v;
    float prod = v * att_l;
#pragma unroll
    for (int mm = 32; mm; mm >>= 1) prod += __shfl_xor(prod, mm);
    if (lane == 0) {
      p_sh[e] = prod;
      atomicMax(&m_sh[tg], flipf(prod));
    }
  }
  __syncthreads();

  for (int e = tid; e < ET; e += 256) {
    int tg = st_sh[e] >> 16;
    p_sh[e] = expf(p_sh[e] - unflipf(m_sh[tg]));
  }
  __syncthreads();

#pragma unroll 1
  for (int n = wid; n < NN; n += 4) {
    int o0 = csr_off[n], o1 = csr_off[n + 1];
    float acc = 0.f, z = 0.f;
    for (int i = o0; i < o1; ++i) {
      float p = p_sh[i];
      int s = st_sh[i] & 0xffff;
      acc += p * xl_sh[s * HH + lane];
      z += p;
    }
    float o = acc / z + bo_l;
    hout[base + n * HH + lane] = fmaxf(o, 0.f);
  }
}

// ---------------- GRU stage A: gi = hbuf @ Wih^T + bih  (batched GEMM) -------
// R5: same LDS-broadcast C=3 design as R4 (the arithmetic was right: DS
// ~3-12K cyc << VALU 24.6K cyc/wave) with the spill fixed:
//  - amdgpu_waves_per_eu(2,2): max occupancy pinned at the 2 waves/SIMD the
//    grid gives anyway -> allocator has zero incentive to shrink below the
//    ~215 VGPRs this needs (R4: capped 128, spilled ~70 floats, 1.5 GB of
//    scratch FETCH, VALUBusy 3.7%).
//  - pressure peaks serialized: staging burst (unroll 4) fully retired
//    before the 192 weight loads issue; row loop unroll 1.
__global__ __launch_bounds__(64)
__attribute__((amdgpu_waves_per_eu(2, 2)))
void gi_proj_kernel(
    const float* __restrict__ hin, const float* __restrict__ Wih,
    const float* __restrict__ bih, float* __restrict__ gi) {
  __shared__ float hsh[64 * HH];       // 16 KB
  int j = threadIdx.x;                 // output column 0..63
  int row0 = blockIdx.x * 64;
  {
    const float4* src4 = (const float4*)(hin + (size_t)row0 * HH);
    float4* dst4 = (float4*)hsh;
#pragma unroll 4
    for (int i = 0; i < 16; ++i)
      dst4[i * 64 + j] = src4[i * 64 + j];   // coalesced 1 KB per instr
  }
  __syncthreads();
  float wr[HH], wz[HH], wn[HH];
  {
    const float4* s0 = (const float4*)(Wih + (size_t)(0 * 64 + j) * HH);
    const float4* s1 = (const float4*)(Wih + (size_t)(1 * 64 + j) * HH);
    const float4* s2 = (const float4*)(Wih + (size_t)(2 * 64 + j) * HH);
#pragma unroll
    for (int i = 0; i < HH / 4; ++i) {
      *(float4*)&wr[4 * i] = s0[i];
      *(float4*)&wz[4 * i] = s1[i];
      *(float4*)&wn[4 * i] = s2[i];
    }
  }
  float br_ = bih[j], bz_ = bih[64 + j], bn_ = bih[128 + j];
#pragma unroll 1
  for (int r = 0; r < 64; ++r) {
    float ar0 = br_, ar1 = 0.f, az0 = bz_, az1 = 0.f, an0 = bn_, an1 = 0.f;
#pragma unroll
    for (int k = 0; k < HH; k += 4) {
      float4 hb = *(const float4*)&hsh[r * HH + k];   // uniform broadcast read
      ar0 += hb.x * wr[k + 0]; az0 += hb.x * wz[k + 0]; an0 += hb.x * wn[k + 0];
      ar1 += hb.y * wr[k + 1]; az1 += hb.y * wz[k + 1]; an1 += hb.y * wn[k + 1];
      ar0 += hb.z * wr[k + 2]; az0 += hb.z * wz[k + 2]; an0 += hb.z * wn[k + 2];
      ar1 += hb.w * wr[k + 3]; az1 += hb.w * wz[k + 3]; an1 += hb.w * wn[k + 3];
    }
    size_t o = (size_t)(row0 + r) * 192;
    gi[o + j]       = ar0 + ar1;         // 3x 256 B coalesced stores
    gi[o + 64 + j]  = az0 + az1;
    gi[o + 128 + j] = an0 + an1;
  }
}

// ---------------- GRU stage B: recurrence, one wave per sequence -------------
// 2048 blocks x 64 threads; zero cross-wave traffic. Lane j holds Whh rows
// {j, 64+j, 128+j} (192 floats; amdgpu_waves_per_eu(2,2) pins the budget so
// they stay register-resident). h broadcast via 256 B LDS hsh + uniform
// float4 reads. gi streamed from global with depth-2 prefetch. 2048 waves =
// chip-resident in one round.
__global__ __launch_bounds__(64)
__attribute__((amdgpu_waves_per_eu(2, 2)))
void gru_rec_kernel(
    const float* __restrict__ gi,
    const float* __restrict__ Whh, const float* __restrict__ bhh,
    const float* __restrict__ oW1, const float* __restrict__ ob1,
    const float* __restrict__ oW2, const float* __restrict__ ob2,
    const float* __restrict__ dW1, const float* __restrict__ db1,
    const float* __restrict__ dW2, const float* __restrict__ db2,
    float* __restrict__ out) {
  __shared__ float hsh[HH];                    // 256 B h broadcast buffer
  int lane = threadIdx.x;                      // 0..63
  int seq = blockIdx.x;                        // b*N + n
  int b = seq >> 7, n = seq & (NN - 1);

  float wr[HH], wz[HH], wn[HH];
  {
    const float4* s0 = (const float4*)(Whh + (size_t)(0 * 64 + lane) * HH);
    const float4* s1 = (const float4*)(Whh + (size_t)(1 * 64 + lane) * HH);
    const float4* s2 = (const float4*)(Whh + (size_t)(2 * 64 + lane) * HH);
#pragma unroll
    for (int i = 0; i < HH / 4; ++i) {
      *(float4*)&wr[4 * i] = s0[i];
      *(float4*)&wz[4 * i] = s1[i];
      *(float4*)&wn[4 * i] = s2[i];
    }
  }
  float br_ = bhh[lane], bz_ = bhh[64 + lane], bn_ = bhh[128 + lane];

  const float* gbase = gi + ((size_t)b * SS * NN + (size_t)n) * 192;  // +t*NN*192
  // depth-2 software pipeline on gi loads
  float gir = gbase[lane], giz = gbase[64 + lane], gin = gbase[128 + lane];
  const float* g1 = gbase + (size_t)NN * 192;
  float pir = g1[lane], piz = g1[64 + lane], pin = g1[128 + lane];
  float hj = 0.f;
  hsh[lane] = 0.f;
  __syncthreads();

#pragma unroll 1
  for (int t = 0; t < SS; ++t) {
    float qir = 0.f, qiz = 0.f, qin = 0.f;
    if (t + 2 < SS) {
      const float* g2 = gbase + (size_t)(t + 2) * NN * 192;
      qir = g2[lane]; qiz = g2[64 + lane]; qin = g2[128 + lane];
    }
    float ar0 = br_, ar1 = 0.f, az0 = bz_, az1 = 0.f, an0 = bn_, an1 = 0.f;
#pragma unroll
    for (int k = 0; k < HH; k += 4) {
      float4 hb = *(const float4*)(hsh + k);   // uniform broadcast read
      ar0 += hb.x * wr[k + 0]; az0 += hb.x * wz[k + 0]; an0 += hb.x * wn[k + 0];
      ar1 += hb.y * wr[k + 1]; az1 += hb.y * wz[k + 1]; an1 += hb.y * wn[k + 1];
      ar0 += hb.z * wr[k + 2]; az0 += hb.z * wz[k + 2]; an0 += hb.z * wn[k + 2];
      ar1 += hb.w * wr[k + 3]; az1 += hb.w * wz[k + 3]; an1 += hb.w * wn[k + 3];
    }
    float r  = sigmoidf_(gir + ar0 + ar1);
    float z  = sigmoidf_(giz + az0 + az1);
    float nn_ = tanhf(gin + r * (an0 + an1));
    hj = (1.f - z) * nn_ + z * hj;
    hsh[lane] = hj;                            // reads of this step already
    __syncthreads();                           // retired (hb consumed above)
    gir = pir; giz = piz; gin = pin;
    pir = qir; piz = qiz; pin = qin;
  }

  // ---- fused heads: lanes 0..31 = order head, 32..63 = demand head ----
  int half = lane >> 5, jp = lane & 31;
  const float* W1 = half ? dW1 : oW1;
  const float* b1 = half ? db1 : ob1;
  const float* W2 = half ? dW2 : oW2;
  const float* b2 = half ? db2 : ob2;
  float wv[HH];
#pragma unroll
  for (int i = 0; i < HH / 4; ++i)
    *(float4*)&wv[4 * i] = ((const float4*)(W1 + jp * HH))[i];
  float acc = b1[jp];
#pragma unroll
  for (int k = 0; k < HH; k += 4) {
    float4 hb = *(const float4*)(hsh + k);     // final h broadcast
    acc += hb.x * wv[k + 0];
    acc += hb.y * wv[k + 1];
    acc += hb.z * wv[k + 2];
    acc += hb.w * wv[k + 3];
  }
  float val = fmaxf(acc, 0.f) * W2[jp];
  val += __shfl_down(val, 16, 32);
  val += __shfl_down(val, 8, 32);
  val += __shfl_down(val, 4, 32);
  val += __shfl_down(val, 2, 32);
  val += __shfl_down(val, 1, 32);
  if (jp == 0) out[half * (BB * NN) + seq] = val + b2[0];
}

// ---------------- fallback GRU (used if ws too small for gi) -----------------
__global__ __launch_bounds__(192, 3) void gru_fused_kernel(
    const float* __restrict__ hbuf,
    const float* __restrict__ Wih, const float* __restrict__ Whh,
    const float* __restrict__ bih, const float* __restrict__ bhh,
    const float* __restrict__ oW1, const float* __restrict__ ob1,
    const float* __restrict__ oW2, const float* __restrict__ ob2,
    const float* __restrict__ dW1, const float* __restrict__ db1,
    const float* __restrict__ dW2, const float* __restrict__ db2,
    float* __restrict__ out) {
  __shared__ float gi_sh[SS * 3 * HH];   // 48 KB  [t][gate][j]
  __shared__ float exch[2][3][HH];       // double-buffered gh exchange

  int lane = threadIdx.x & 63;
  int g = (int)threadIdx.x >> 6;
  int seq = blockIdx.x;
  int b = seq >> 7, n = seq & (NN - 1);
  const float* xbase = hbuf + ((size_t)b * SS * NN + (size_t)n) * HH;

  {
    float w[HH];
    const float4* wsrc = (const float4*)(Wih + (size_t)(g * 64 + lane) * HH);
#pragma unroll
    for (int i = 0; i < HH / 4; ++i) *(float4*)&w[4 * i] = wsrc[i];
    float bias = bih[g * 64 + lane];
#pragma unroll 2
    for (int t = 0; t < SS; ++t) {
      const float* xr = xbase + (size_t)t * NN * HH;
      float a0 = bias, a1 = 0.f, a2 = 0.f, a3 = 0.f;
#pragma unroll
      for (int k = 0; k < HH; k += 4) {
        float4 xb = *(const float4*)(xr + k);
        a0 += xb.x * w[k + 0];
        a1 += xb.y * w[k + 1];
        a2 += xb.z * w[k + 2];
        a3 += xb.w * w[k + 3];
      }
      gi_sh[(t * 3 + g) * HH + lane] = (a0 + a1) + (a2 + a3);
    }
  }

  float whh[HH];
  {
    const float4* wsrc = (const float4*)(Whh + (size_t)(g * 64 + lane) * HH);
#pragma unroll
    for (int i = 0; i < HH / 4; ++i) *(float4*)&whh[4 * i] = wsrc[i];
  }
  float bhg = bhh[g * 64 + lane];
  float hj = 0.f;
  __syncthreads();

#pragma unroll 1
  for (int t = 0; t < SS; ++t) {
    float a0 = bhg, a1 = 0.f, a2 = 0.f, a3 = 0.f;
#pragma unroll
    for (int k = 0; k < HH; k += 4) {
      a0 += readlane_f(hj, k + 0) * whh[k + 0];
      a1 += readlane_f(hj, k + 1) * whh[k + 1];
      a2 += readlane_f(hj, k + 2) * whh[k + 2];
      a3 += readlane_f(hj, k + 3) * whh[k + 3];
    }
    float gh = (a0 + a1) + (a2 + a3);
    int slot = t & 1;
    exch[slot][g][lane] = gh;
    __syncthreads();
    float ghr = exch[slot][0][lane];
    float ghz = exch[slot][1][lane];
    float ghn = exch[slot][2][lane];
    float gir = gi_sh[(t * 3 + 0) * HH + lane];
    float giz = gi_sh[(t * 3 + 1) * HH + lane];
    float gin = gi_sh[(t * 3 + 2) * HH + lane];
    float r  = sigmoidf_(gir + ghr);
    float z  = sigmoidf_(giz + ghz);
    float nn_ = tanhf(gin + r * ghn);
    hj = (1.f - z) * nn_ + z * hj;
  }

  if (g == 0) {
    int half = lane >> 5, jp = lane & 31;
    const float* W1 = half ? dW1 : oW1;
    const float* b1 = half ? db1 : ob1;
    const float* W2 = half ? dW2 : oW2;
    const float* b2 = half ? db2 : ob2;
    float wv[HH];
#pragma unroll
    for (int i = 0; i < HH / 4; ++i)
      *(float4*)&wv[4 * i] = ((const float4*)(W1 + jp * HH))[i];
    float acc = b1[jp];
#pragma unroll
    for (int k = 0; k < HH; ++k)
      acc += readlane_f(hj, k) * wv[k];
    float val = fmaxf(acc, 0.f) * W2[jp];
    val += __shfl_down(val, 16, 32);
    val += __shfl_down(val, 8, 32);
    val += __shfl_down(val, 4, 32);
    val += __shfl_down(val, 2, 32);
    val += __shfl_down(val, 1, 32);
    if (jp == 0) out[half * (BB * NN) + seq] = val + b2[0];
  }
}

// ---------------- launch -----------------------------------------------------
extern "C" void kernel_launch(void* const* d_in, const int* in_sizes, int n_in,
                              void* d_out, int out_size, void* d_ws, size_t ws_size,
                              hipStream_t stream) {
  const float* x       = (const float*)d_in[0];
  const int*   ei      = (const int*)d_in[1];
  const float* in_W    = (const float*)d_in[2];
  const float* in_b    = (const float*)d_in[3];
  const float* gat_Wl  = (const float*)d_in[4];
  const float* gat_bl  = (const float*)d_in[5];
  const float* gat_Wr  = (const float*)d_in[6];
  const float* gat_br  = (const float*)d_in[7];
  const float* gat_att = (const float*)d_in[8];
  const float* gat_bias= (const float*)d_in[9];
  const float* gru_Wih = (const float*)d_in[10];
  const float* gru_Whh = (const float*)d_in[11];
  const float* gru_bih = (const float*)d_in[12];
  const float* gru_bhh = (const float*)d_in[13];
  const float* oh_W1   = (const float*)d_in[14];
  const float* oh_b1   = (const float*)d_in[15];
  const float* oh_W2   = (const float*)d_in[16];
  const float* oh_b2   = (const float*)d_in[17];
  const float* dh_W1   = (const float*)d_in[18];
  const float* dh_b1   = (const float*)d_in[19];
  const float* dh_W2   = (const float*)d_in[20];
  const float* dh_b2   = (const float*)d_in[21];
  float* out = (float*)d_out;

  char* ws = (char*)d_ws;
  size_t hfloats = (size_t)BB * SS * NN * HH;           // 8.39M floats
  float* hbuf = (float*)ws;
  size_t off_csr = hfloats * sizeof(float);
  size_t off_buf = off_csr + (160 + 2 * ET) * sizeof(int);
  off_buf = (off_buf + 255) & ~(size_t)255;             // 256B align
  int* csr_off = (int*)(ws + off_csr);
  int* csr_src = csr_off + 160;
  int* csr_tgt = csr_src + ET;
  float* xlbuf = (float*)(ws + off_buf);
  float* xrbuf = xlbuf + hfloats;
  size_t need_gat = off_buf + 2 * hfloats * sizeof(float);
  bool big_gat = (ws_size >= need_gat);
  // gi buffer overlays xl/xr (dead after the GAT layers): RT*192 floats
  float* gibuf = (float*)(ws + off_buf);
  size_t need_gru = off_buf + (size_t)RT * 192 * sizeof(float);  // ~134 MB
  bool big_gru = (ws_size >= need_gru);

  setup_csr_kernel<<<1, 256, 0, stream>>>(ei, csr_off, csr_src, csr_tgt);
  input_proj_kernel<<<(BB * SS * NN) / (4 * 32), 256, 0, stream>>>(x, in_W, in_b, hbuf);
  for (int l = 0; l < LLAYERS; ++l) {
    if (big_gat) {
      xlxr_kernel<<<RT / 64, 64, 0, stream>>>(
          hbuf, gat_Wl + l * HH * HH, gat_bl + l * HH,
          gat_Wr + l * HH * HH, gat_br + l * HH, xlbuf, xrbuf);
      gat_edge_kernel<<<BB * SS, 256, 0, stream>>>(
          xlbuf, xrbuf, hbuf, csr_off, csr_src, csr_tgt,
          gat_att + l * HH, gat_bias + l * HH);
    } else {
      gat_fused_kernel<<<BB * SS, 256, 0, stream>>>(
          hbuf, hbuf, csr_off, csr_src, csr_tgt,
          gat_Wl + l * HH * HH, gat_bl + l * HH,
          gat_Wr + l * HH * HH, gat_br + l * HH,
          gat_att + l * HH, gat_bias + l * HH);
    }
  }
  if (big_gru) {
    gi_proj_kernel<<<RT / 64, 64, 0, stream>>>(hbuf, gru_Wih, gru_bih, gibuf);
    gru_rec_kernel<<<BB * NN, 64, 0, stream>>>(
        gibuf, gru_Whh, gru_bhh,
        oh_W1, oh_b1, oh_W2, oh_b2, dh_W1, dh_b1, dh_W2, dh_b2, out);
  } else {
    gru_fused_kernel<<<BB * NN, 192, 0, stream>>>(
        hbuf, gru_Wih, gru_Whh, gru_bih, gru_bhh,
        oh_W1, oh_b1, oh_W2, oh_b2, dh_W1, dh_b1, dh_W2, dh_b2, out);
  }
}

// Round 6
// 604.942 us; speedup vs baseline: 2.9314x; 2.9291x over previous
//
#include <hip/hip_runtime.h>
#include <math.h>

#define BB 16
#define SS 64
#define NN 128
#define FF 16
#define HH 64
#define EE 1024
#define ET 1152   // EE + NN self-loops
#define LLAYERS 2
#define XPAD 65   // padded LDS row stride for xl/xr (bank = (s+h)%32)
#define RT (BB * SS * NN)   // 131072 GRU input rows

__device__ __forceinline__ float readlane_f(float v, int k) {
  return __int_as_float(__builtin_amdgcn_readlane(__float_as_int(v), k));
}
// monotonic float<->uint mapping for atomicMax-based float max
__device__ __forceinline__ unsigned flipf(float f) {
  unsigned u = __float_as_uint(f);
  unsigned mask = (u & 0x80000000u) ? 0xFFFFFFFFu : 0x80000000u;
  return u ^ mask;
}
__device__ __forceinline__ float unflipf(unsigned u) {
  unsigned b = (u & 0x80000000u) ? (u ^ 0x80000000u) : ~u;
  return __uint_as_float(b);
}
__device__ __forceinline__ float sigmoidf_(float x) { return 1.f / (1.f + expf(-x)); }

// ---------------- CSR setup (graph is identical for every (b,s)) -------------
__global__ void setup_csr_kernel(const int* __restrict__ ei,
                                 int* __restrict__ off,
                                 int* __restrict__ csrc,
                                 int* __restrict__ ctgt) {
  __shared__ int deg[NN], cur[NN], offs[NN + 1];
  int tid = threadIdx.x;
  if (tid < NN) deg[tid] = 0;
  __syncthreads();
  for (int e = tid; e < ET; e += 256) {
    int tg = (e < EE) ? ei[EE + e] : (e - EE);
    atomicAdd(&deg[tg], 1);
  }
  __syncthreads();
  if (tid == 0) {
    int s = 0;
    for (int i = 0; i < NN; ++i) { offs[i] = s; s += deg[i]; }
    offs[NN] = s;
  }
  __syncthreads();
  if (tid < NN) cur[tid] = offs[tid];
  if (tid <= NN) off[tid] = offs[tid];
  __syncthreads();
  for (int e = tid; e < ET; e += 256) {
    int sv, tg;
    if (e < EE) { sv = ei[e]; tg = ei[EE + e]; }
    else        { sv = e - EE; tg = e - EE; }
    int pos = atomicAdd(&cur[tg], 1);
    csrc[pos] = sv;
    ctgt[pos] = tg;
  }
}

// ---------------- input projection: h = x @ W^T + b --------------------------
__global__ __launch_bounds__(256) void input_proj_kernel(
    const float* __restrict__ x, const float* __restrict__ W,
    const float* __restrict__ bvec, float* __restrict__ h) {
  int lane = threadIdx.x & 63;
  int wid = threadIdx.x >> 6;
  float wreg[FF];
#pragma unroll
  for (int i = 0; i < FF / 4; ++i)
    *(float4*)&wreg[4 * i] = ((const float4*)(W + lane * FF))[i];
  float bias = bvec[lane];
  int row0 = __builtin_amdgcn_readfirstlane((blockIdx.x * 4 + wid) * 32);
#pragma unroll 2
  for (int r = 0; r < 32; ++r) {
    int row = row0 + r;
    const float* xr = x + row * FF;
    float acc = bias;
#pragma unroll
    for (int f = 0; f < FF; ++f) acc += xr[f] * wreg[f];
    h[row * HH + lane] = acc;
  }
}

// ---------------- GAT kernel A: xl = h@Wl^T+bl, xr = h@Wr^T+br ---------------
// R6: C=1 spill-proof variant. 128-thread blocks = 2 waves; wave 0 owns xl
// (Wl), wave 1 owns xr (Wr). ONE 64-float weight row per lane -> natural
// VGPR need ~90 < the 128 cliff the allocator enforces regardless of
// attributes (R4/R5: 128-float+ arrays => cap at 128 + 1.5 GB scratch FETCH,
// VALUBusy 3.6%). h rows staged cooperatively into LDS (coalesced float4),
// matvec operand = uniform ds_read_b128 broadcast (conflict-free).
__global__ __launch_bounds__(128) void xlxr_kernel(
    const float* __restrict__ hin,
    const float* __restrict__ Wl, const float* __restrict__ bl,
    const float* __restrict__ Wr, const float* __restrict__ br,
    float* __restrict__ xl, float* __restrict__ xr) {
  __shared__ float hsh[64 * HH];       // 16 KB: 64 staged h rows
  int tid = threadIdx.x;
  int j = tid & 63;                    // output column
  int w = tid >> 6;                    // 0 -> xl, 1 -> xr
  int row0 = blockIdx.x * 64;
  {
    const float4* src4 = (const float4*)(hin + (size_t)row0 * HH);
    float4* dst4 = (float4*)hsh;
#pragma unroll
    for (int i = 0; i < 8; ++i)
      dst4[i * 128 + tid] = src4[i * 128 + tid];   // coalesced 2 KB per instr
  }
  __syncthreads();
  const float* W  = w ? Wr : Wl;
  const float* bv = w ? br : bl;
  float* outp     = w ? xr : xl;
  float wreg[HH];
  {
    const float4* ws_ = (const float4*)(W + (size_t)j * HH);
#pragma unroll
    for (int i = 0; i < HH / 4; ++i) *(float4*)&wreg[4 * i] = ws_[i];
  }
  float bias = bv[j];
#pragma unroll 1
  for (int r = 0; r < 64; ++r) {
    float a0 = bias, a1 = 0.f, a2 = 0.f, a3 = 0.f;
#pragma unroll
    for (int k = 0; k < HH; k += 4) {
      float4 hb = *(const float4*)&hsh[r * HH + k];   // uniform broadcast read
      a0 += hb.x * wreg[k + 0];
      a1 += hb.y * wreg[k + 1];
      a2 += hb.z * wreg[k + 2];
      a3 += hb.w * wreg[k + 3];
    }
    outp[(size_t)(row0 + r) * HH + j] = (a0 + a1) + (a2 + a3);  // 256 B coalesced
  }
}

// ---------------- GAT kernel B: edge logits + softmax + aggregate ------------
__global__ __launch_bounds__(256) void gat_edge_kernel(
    const float* __restrict__ xl_g, const float* __restrict__ xr_g,
    float* __restrict__ hout,
    const int* __restrict__ csr_off, const int* __restrict__ csr_src,
    const int* __restrict__ csr_tgt,
    const float* __restrict__ att, const float* __restrict__ bo) {
  __shared__ float xl_sh[NN * XPAD];   // 33.3 KB
  __shared__ float xr_sh[NN * XPAD];   // 33.3 KB
  __shared__ float p_sh[ET];
  __shared__ int st_sh[ET];
  __shared__ unsigned m_sh[NN];
  int tid = threadIdx.x, lane = tid & 63, wid = tid >> 6;
  int base = blockIdx.x * (NN * HH);

  // stage xl/xr with padded stride
#pragma unroll 1
  for (int i = tid * 4; i < NN * HH; i += 256 * 4) {
    int row = i >> 6, h = i & 63;
    float4 vl = *(const float4*)(xl_g + base + i);
    float4 vr = *(const float4*)(xr_g + base + i);
    float* dl = xl_sh + row * XPAD + h;
    float* dr = xr_sh + row * XPAD + h;
    dl[0] = vl.x; dl[1] = vl.y; dl[2] = vl.z; dl[3] = vl.w;
    dr[0] = vr.x; dr[1] = vr.y; dr[2] = vr.z; dr[3] = vr.w;
  }
  for (int i = tid; i < ET; i += 256)
    st_sh[i] = csr_src[i] | (csr_tgt[i] << 16);
  if (tid < NN) m_sh[tid] = 0u;
  __syncthreads();

  // pass 1: thread-per-edge attention logit + segment max
#pragma unroll 1
  for (int e = tid; e < ET; e += 256) {
    int st = st_sh[e];
    int s = st & 0xffff, tg = st >> 16;
    const float* xlr = xl_sh + s * XPAD;
    const float* xrr = xr_sh + tg * XPAD;
    float a0 = 0.f, a1 = 0.f, a2 = 0.f, a3 = 0.f;
#pragma unroll
    for (int h = 0; h < HH; h += 4) {
      float v0 = xlr[h + 0] + xrr[h + 0]; v0 = (v0 > 0.f) ? v0 : 0.2f * v0;
      float v1 = xlr[h + 1] + xrr[h + 1]; v1 = (v1 > 0.f) ? v1 : 0.2f * v1;
      float v2 = xlr[h + 2] + xrr[h + 2]; v2 = (v2 > 0.f) ? v2 : 0.2f * v2;
      float v3 = xlr[h + 3] + xrr[h + 3]; v3 = (v3 > 0.f) ? v3 : 0.2f * v3;
      a0 += v0 * att[h + 0];
      a1 += v1 * att[h + 1];
      a2 += v2 * att[h + 2];
      a3 += v3 * att[h + 3];
    }
    float a = (a0 + a1) + (a2 + a3);
    p_sh[e] = a;
    atomicMax(&m_sh[tg], flipf(a));
  }
  __syncthreads();

  // pass 2: stabilized exp
  for (int e = tid; e < ET; e += 256) {
    int tg = st_sh[e] >> 16;
    p_sh[e] = expf(p_sh[e] - unflipf(m_sh[tg]));
  }
  __syncthreads();

  // gather: wave per target node, CSR-contiguous edge segment
  float bo_l = bo[lane];
#pragma unroll 1
  for (int n = wid; n < NN; n += 4) {
    int o0 = __builtin_amdgcn_readfirstlane(csr_off[n]);
    int o1 = __builtin_amdgcn_readfirstlane(csr_off[n + 1]);
    float acc = 0.f, z = 0.f;
    for (int i = o0; i < o1; ++i) {
      float p = p_sh[i];
      int s = st_sh[i] & 0xffff;
      acc += p * xl_sh[s * XPAD + lane];
      z += p;
    }
    float o = acc / z + bo_l;
    hout[base + n * HH + lane] = fmaxf(o, 0.f);
  }
}

// ---------------- fallback fused GAT (used if ws too small) ------------------
__device__ __forceinline__ void gemm_half(
    const float* __restrict__ hin, int base,
    const float* __restrict__ W, const float* __restrict__ bvec,
    float* __restrict__ out_sh, int half, int lane) {
  float wreg[HH];
#pragma unroll
  for (int i = 0; i < HH / 4; ++i)
    *(float4*)&wreg[4 * i] = ((const float4*)(W + lane * HH))[i];
  float bias = bvec[lane];
  int n0 = __builtin_amdgcn_readfirstlane(half * 64);
#pragma unroll 1
  for (int nd = 0; nd < 64; ++nd) {
    int node = n0 + nd;
    const float* hrow = hin + base + node * HH;
    float a0 = bias, a1 = 0.f, a2 = 0.f, a3 = 0.f;
#pragma unroll
    for (int f = 0; f < HH; f += 4) {
      a0 += hrow[f + 0] * wreg[f + 0];
      a1 += hrow[f + 1] * wreg[f + 1];
      a2 += hrow[f + 2] * wreg[f + 2];
      a3 += hrow[f + 3] * wreg[f + 3];
    }
    out_sh[node * HH + lane] = (a0 + a1) + (a2 + a3);
  }
}

__global__ __launch_bounds__(256) void gat_fused_kernel(
    const float* __restrict__ hin, float* __restrict__ hout,
    const int* __restrict__ csr_off, const int* __restrict__ csr_src,
    const int* __restrict__ csr_tgt,
    const float* __restrict__ Wl, const float* __restrict__ bl,
    const float* __restrict__ Wr, const float* __restrict__ br,
    const float* __restrict__ att, const float* __restrict__ bo) {
  __shared__ float xl_sh[NN * HH];
  __shared__ float xr_sh[NN * HH];
  __shared__ float p_sh[ET];
  __shared__ int st_sh[ET];
  __shared__ unsigned m_sh[NN];
  int tid = threadIdx.x, lane = tid & 63, wid = tid >> 6;
  int base = blockIdx.x * (NN * HH);

  for (int i = tid; i < ET; i += 256)
    st_sh[i] = csr_src[i] | (csr_tgt[i] << 16);
  if (tid < NN) m_sh[tid] = 0u;

  if (wid < 2) gemm_half(hin, base, Wl, bl, xl_sh, wid & 1, lane);
  else         gemm_half(hin, base, Wr, br, xr_sh, wid & 1, lane);

  float att_l = att[lane];
  float bo_l = bo[lane];
  __syncthreads();

#pragma unroll 1
  for (int e = wid; e < ET; e += 4) {
    int st = st_sh[e];
    int s = st & 0xffff, tg = st >> 16;
    float v = xl_sh[s * HH + lane] + xr_sh[tg * HH + lane];
    v = (v > 0.f) ? v : 0.2f * v;
    float prod = v * att_l;
#pragma unroll
    for (int mm = 32; mm; mm >>= 1) prod += __shfl_xor(prod, mm);
    if (lane == 0) {
      p_sh[e] = prod;
      atomicMax(&m_sh[tg], flipf(prod));
    }
  }
  __syncthreads();

  for (int e = tid; e < ET; e += 256) {
    int tg = st_sh[e] >> 16;
    p_sh[e] = expf(p_sh[e] - unflipf(m_sh[tg]));
  }
  __syncthreads();

#pragma unroll 1
  for (int n = wid; n < NN; n += 4) {
    int o0 = csr_off[n], o1 = csr_off[n + 1];
    float acc = 0.f, z = 0.f;
    for (int i = o0; i < o1; ++i) {
      float p = p_sh[i];
      int s = st_sh[i] & 0xffff;
      acc += p * xl_sh[s * HH + lane];
      z += p;
    }
    float o = acc / z + bo_l;
    hout[base + n * HH + lane] = fmaxf(o, 0.f);
  }
}

// ---------------- GRU stage A: gi = hbuf @ Wih^T + bih  (batched GEMM) -------
// R6: C=1 spill-proof variant. 192-thread blocks = 3 gate-waves; wave g,
// lane j owns output column g*64+j -> ONE 64-float Wih row per lane
// (R2's gru_fused phase-1 proved this size compiles to VGPR=76, no spill).
// 64 h rows staged cooperatively, matvec operand = uniform ds_read_b128
// broadcast. 6144 waves -> ~24 waves/CU of latency hiding (vs 8 before).
__global__ __launch_bounds__(192) void gi_proj_kernel(
    const float* __restrict__ hin, const float* __restrict__ Wih,
    const float* __restrict__ bih, float* __restrict__ gi) {
  __shared__ float hsh[64 * HH];       // 16 KB
  int tid = threadIdx.x;
  int j = tid & 63;                    // output column within gate
  int g = tid >> 6;                    // gate 0..2
  int row0 = blockIdx.x * 64;
  {
    const float4* src4 = (const float4*)(hin + (size_t)row0 * HH);
    float4* dst4 = (float4*)hsh;
#pragma unroll 1
    for (int i = tid; i < 1024; i += 192)
      dst4[i] = src4[i];               // coalesced
  }
  __syncthreads();
  float wreg[HH];
  {
    const float4* ws_ = (const float4*)(Wih + (size_t)(g * 64 + j) * HH);
#pragma unroll
    for (int i = 0; i < HH / 4; ++i) *(float4*)&wreg[4 * i] = ws_[i];
  }
  float bias = bih[g * 64 + j];
#pragma unroll 1
  for (int r = 0; r < 64; ++r) {
    float a0 = bias, a1 = 0.f, a2 = 0.f, a3 = 0.f;
#pragma unroll
    for (int k = 0; k < HH; k += 4) {
      float4 hb = *(const float4*)&hsh[r * HH + k];   // uniform broadcast read
      a0 += hb.x * wreg[k + 0];
      a1 += hb.y * wreg[k + 1];
      a2 += hb.z * wreg[k + 2];
      a3 += hb.w * wreg[k + 3];
    }
    gi[(size_t)(row0 + r) * 192 + g * 64 + j] = (a0 + a1) + (a2 + a3);
  }
}

// ---------------- GRU stage B: recurrence, one wave per sequence -------------
// R3 configuration verbatim (best-evidenced: ~92 us, no spill at
// __launch_bounds__(64,2) WITHOUT LDS staging in the kernel). 2048 blocks x
// 64 threads; zero barriers, zero cross-wave traffic. Lane j holds Whh rows
// {j, 64+j, 128+j} (192 floats). h broadcast = v_readlane of the wave's own
// hj. gi streamed with depth-2 prefetch. 2048 waves chip-resident in one
// round.
__global__ __launch_bounds__(64, 2) void gru_rec_kernel(
    const float* __restrict__ gi,
    const float* __restrict__ Whh, const float* __restrict__ bhh,
    const float* __restrict__ oW1, const float* __restrict__ ob1,
    const float* __restrict__ oW2, const float* __restrict__ ob2,
    const float* __restrict__ dW1, const float* __restrict__ db1,
    const float* __restrict__ dW2, const float* __restrict__ db2,
    float* __restrict__ out) {
  int lane = threadIdx.x;                      // 0..63
  int seq = blockIdx.x;                        // b*N + n
  int b = seq >> 7, n = seq & (NN - 1);

  float wr[HH], wz[HH], wn[HH];
  {
    const float4* s0 = (const float4*)(Whh + (size_t)(0 * 64 + lane) * HH);
    const float4* s1 = (const float4*)(Whh + (size_t)(1 * 64 + lane) * HH);
    const float4* s2 = (const float4*)(Whh + (size_t)(2 * 64 + lane) * HH);
#pragma unroll
    for (int i = 0; i < HH / 4; ++i) {
      *(float4*)&wr[4 * i] = s0[i];
      *(float4*)&wz[4 * i] = s1[i];
      *(float4*)&wn[4 * i] = s2[i];
    }
  }
  float br_ = bhh[lane], bz_ = bhh[64 + lane], bn_ = bhh[128 + lane];

  const float* gbase = gi + ((size_t)b * SS * NN + (size_t)n) * 192;  // +t*NN*192
  // depth-2 software pipeline on gi loads
  float gir = gbase[lane], giz = gbase[64 + lane], gin = gbase[128 + lane];
  const float* g1 = gbase + (size_t)NN * 192;
  float pir = g1[lane], piz = g1[64 + lane], pin = g1[128 + lane];
  float hj = 0.f;

#pragma unroll 1
  for (int t = 0; t < SS; ++t) {
    float qir = 0.f, qiz = 0.f, qin = 0.f;
    if (t + 2 < SS) {
      const float* g2 = gbase + (size_t)(t + 2) * NN * 192;
      qir = g2[lane]; qiz = g2[64 + lane]; qin = g2[128 + lane];
    }
    float ar0 = br_, ar1 = 0.f, az0 = bz_, az1 = 0.f, an0 = bn_, an1 = 0.f;
#pragma unroll
    for (int k = 0; k < HH; k += 2) {
      float h0 = readlane_f(hj, k), h1 = readlane_f(hj, k + 1);
      ar0 += h0 * wr[k];     az0 += h0 * wz[k];     an0 += h0 * wn[k];
      ar1 += h1 * wr[k + 1]; az1 += h1 * wz[k + 1]; an1 += h1 * wn[k + 1];
    }
    float r  = sigmoidf_(gir + ar0 + ar1);
    float z  = sigmoidf_(giz + az0 + az1);
    float nn_ = tanhf(gin + r * (an0 + an1));
    hj = (1.f - z) * nn_ + z * hj;
    gir = pir; giz = piz; gin = pin;
    pir = qir; piz = qiz; pin = qin;
  }

  // ---- fused heads: lanes 0..31 = order head, 32..63 = demand head ----
  int half = lane >> 5, jp = lane & 31;
  const float* W1 = half ? dW1 : oW1;
  const float* b1 = half ? db1 : ob1;
  const float* W2 = half ? dW2 : oW2;
  const float* b2 = half ? db2 : ob2;
  float wv[HH];
#pragma unroll
  for (int i = 0; i < HH / 4; ++i)
    *(float4*)&wv[4 * i] = ((const float4*)(W1 + jp * HH))[i];
  float acc = b1[jp];
#pragma unroll
  for (int k = 0; k < HH; ++k)
    acc += readlane_f(hj, k) * wv[k];            // broadcast from own h copy
  float val = fmaxf(acc, 0.f) * W2[jp];
  val += __shfl_down(val, 16, 32);
  val += __shfl_down(val, 8, 32);
  val += __shfl_down(val, 4, 32);
  val += __shfl_down(val, 2, 32);
  val += __shfl_down(val, 1, 32);
  if (jp == 0) out[half * (BB * NN) + seq] = val + b2[0];
}

// ---------------- fallback GRU (used if ws too small for gi) -----------------
__global__ __launch_bounds__(192, 3) void gru_fused_kernel(
    const float* __restrict__ hbuf,
    const float* __restrict__ Wih, const float* __restrict__ Whh,
    const float* __restrict__ bih, const float* __restrict__ bhh,
    const float* __restrict__ oW1, const float* __restrict__ ob1,
    const float* __restrict__ oW2, const float* __restrict__ ob2,
    const float* __restrict__ dW1, const float* __restrict__ db1,
    const float* __restrict__ dW2, const float* __restrict__ db2,
    float* __restrict__ out) {
  __shared__ float gi_sh[SS * 3 * HH];   // 48 KB  [t][gate][j]
  __shared__ float exch[2][3][HH];       // double-buffered gh exchange

  int lane = threadIdx.x & 63;
  int g = (int)threadIdx.x >> 6;
  int seq = blockIdx.x;
  int b = seq >> 7, n = seq & (NN - 1);
  const float* xbase = hbuf + ((size_t)b * SS * NN + (size_t)n) * HH;

  {
    float w[HH];
    const float4* wsrc = (const float4*)(Wih + (size_t)(g * 64 + lane) * HH);
#pragma unroll
    for (int i = 0; i < HH / 4; ++i) *(float4*)&w[4 * i] = wsrc[i];
    float bias = bih[g * 64 + lane];
#pragma unroll 2
    for (int t = 0; t < SS; ++t) {
      const float* xr = xbase + (size_t)t * NN * HH;
      float a0 = bias, a1 = 0.f, a2 = 0.f, a3 = 0.f;
#pragma unroll
      for (int k = 0; k < HH; k += 4) {
        float4 xb = *(const float4*)(xr + k);
        a0 += xb.x * w[k + 0];
        a1 += xb.y * w[k + 1];
        a2 += xb.z * w[k + 2];
        a3 += xb.w * w[k + 3];
      }
      gi_sh[(t * 3 + g) * HH + lane] = (a0 + a1) + (a2 + a3);
    }
  }

  float whh[HH];
  {
    const float4* wsrc = (const float4*)(Whh + (size_t)(g * 64 + lane) * HH);
#pragma unroll
    for (int i = 0; i < HH / 4; ++i) *(float4*)&whh[4 * i] = wsrc[i];
  }
  float bhg = bhh[g * 64 + lane];
  float hj = 0.f;
  __syncthreads();

#pragma unroll 1
  for (int t = 0; t < SS; ++t) {
    float a0 = bhg, a1 = 0.f, a2 = 0.f, a3 = 0.f;
#pragma unroll
    for (int k = 0; k < HH; k += 4) {
      a0 += readlane_f(hj, k + 0) * whh[k + 0];
      a1 += readlane_f(hj, k + 1) * whh[k + 1];
      a2 += readlane_f(hj, k + 2) * whh[k + 2];
      a3 += readlane_f(hj, k + 3) * whh[k + 3];
    }
    float gh = (a0 + a1) + (a2 + a3);
    int slot = t & 1;
    exch[slot][g][lane] = gh;
    __syncthreads();
    float ghr = exch[slot][0][lane];
    float ghz = exch[slot][1][lane];
    float ghn = exch[slot][2][lane];
    float gir = gi_sh[(t * 3 + 0) * HH + lane];
    float giz = gi_sh[(t * 3 + 1) * HH + lane];
    float gin = gi_sh[(t * 3 + 2) * HH + lane];
    float r  = sigmoidf_(gir + ghr);
    float z  = sigmoidf_(giz + ghz);
    float nn_ = tanhf(gin + r * ghn);
    hj = (1.f - z) * nn_ + z * hj;
  }

  if (g == 0) {
    int half = lane >> 5, jp = lane & 31;
    const float* W1 = half ? dW1 : oW1;
    const float* b1 = half ? db1 : ob1;
    const float* W2 = half ? dW2 : oW2;
    const float* b2 = half ? db2 : ob2;
    float wv[HH];
#pragma unroll
    for (int i = 0; i < HH / 4; ++i)
      *(float4*)&wv[4 * i] = ((const float4*)(W1 + jp * HH))[i];
    float acc = b1[jp];
#pragma unroll
    for (int k = 0; k < HH; ++k)
      acc += readlane_f(hj, k) * wv[k];
    float val = fmaxf(acc, 0.f) * W2[jp];
    val += __shfl_down(val, 16, 32);
    val += __shfl_down(val, 8, 32);
    val += __shfl_down(val, 4, 32);
    val += __shfl_down(val, 2, 32);
    val += __shfl_down(val, 1, 32);
    if (jp == 0) out[half * (BB * NN) + seq] = val + b2[0];
  }
}

// ---------------- launch -----------------------------------------------------
extern "C" void kernel_launch(void* const* d_in, const int* in_sizes, int n_in,
                              void* d_out, int out_size, void* d_ws, size_t ws_size,
                              hipStream_t stream) {
  const float* x       = (const float*)d_in[0];
  const int*   ei      = (const int*)d_in[1];
  const float* in_W    = (const float*)d_in[2];
  const float* in_b    = (const float*)d_in[3];
  const float* gat_Wl  = (const float*)d_in[4];
  const float* gat_bl  = (const float*)d_in[5];
  const float* gat_Wr  = (const float*)d_in[6];
  const float* gat_br  = (const float*)d_in[7];
  const float* gat_att = (const float*)d_in[8];
  const float* gat_bias= (const float*)d_in[9];
  const float* gru_Wih = (const float*)d_in[10];
  const float* gru_Whh = (const float*)d_in[11];
  const float* gru_bih = (const float*)d_in[12];
  const float* gru_bhh = (const float*)d_in[13];
  const float* oh_W1   = (const float*)d_in[14];
  const float* oh_b1   = (const float*)d_in[15];
  const float* oh_W2   = (const float*)d_in[16];
  const float* oh_b2   = (const float*)d_in[17];
  const float* dh_W1   = (const float*)d_in[18];
  const float* dh_b1   = (const float*)d_in[19];
  const float* dh_W2   = (const float*)d_in[20];
  const float* dh_b2   = (const float*)d_in[21];
  float* out = (float*)d_out;

  char* ws = (char*)d_ws;
  size_t hfloats = (size_t)BB * SS * NN * HH;           // 8.39M floats
  float* hbuf = (float*)ws;
  size_t off_csr = hfloats * sizeof(float);
  size_t off_buf = off_csr + (160 + 2 * ET) * sizeof(int);
  off_buf = (off_buf + 255) & ~(size_t)255;             // 256B align
  int* csr_off = (int*)(ws + off_csr);
  int* csr_src = csr_off + 160;
  int* csr_tgt = csr_src + ET;
  float* xlbuf = (float*)(ws + off_buf);
  float* xrbuf = xlbuf + hfloats;
  size_t need_gat = off_buf + 2 * hfloats * sizeof(float);
  bool big_gat = (ws_size >= need_gat);
  // gi buffer overlays xl/xr (dead after the GAT layers): RT*192 floats
  float* gibuf = (float*)(ws + off_buf);
  size_t need_gru = off_buf + (size_t)RT * 192 * sizeof(float);  // ~134 MB
  bool big_gru = (ws_size >= need_gru);

  setup_csr_kernel<<<1, 256, 0, stream>>>(ei, csr_off, csr_src, csr_tgt);
  input_proj_kernel<<<(BB * SS * NN) / (4 * 32), 256, 0, stream>>>(x, in_W, in_b, hbuf);
  for (int l = 0; l < LLAYERS; ++l) {
    if (big_gat) {
      xlxr_kernel<<<RT / 64, 128, 0, stream>>>(
          hbuf, gat_Wl + l * HH * HH, gat_bl + l * HH,
          gat_Wr + l * HH * HH, gat_br + l * HH, xlbuf, xrbuf);
      gat_edge_kernel<<<BB * SS, 256, 0, stream>>>(
          xlbuf, xrbuf, hbuf, csr_off, csr_src, csr_tgt,
          gat_att + l * HH, gat_bias + l * HH);
    } else {
      gat_fused_kernel<<<BB * SS, 256, 0, stream>>>(
          hbuf, hbuf, csr_off, csr_src, csr_tgt,
          gat_Wl + l * HH * HH, gat_bl + l * HH,
          gat_Wr + l * HH * HH, gat_br + l * HH,
          gat_att + l * HH, gat_bias + l * HH);
    }
  }
  if (big_gru) {
    gi_proj_kernel<<<RT / 64, 192, 0, stream>>>(hbuf, gru_Wih, gru_bih, gibuf);
    gru_rec_kernel<<<BB * NN, 64, 0, stream>>>(
        gibuf, gru_Whh, gru_bhh,
        oh_W1, oh_b1, oh_W2, oh_b2, dh_W1, dh_b1, dh_W2, dh_b2, out);
  } else {
    gru_fused_kernel<<<BB * NN, 192, 0, stream>>>(
        hbuf, gru_Wih, gru_Whh, gru_bih, gru_bhh,
        oh_W1, oh_b1, oh_W2, oh_b2, dh_W1, dh_b1, dh_W2, dh_b2, out);
  }
}